// Round 12
// baseline (644.899 us; speedup 1.0000x reference)
//
#include <hip/hip_runtime.h>
#include <math.h>

#define N_NODES 65536
#define N_EDGES 262144
#define N_GRAPHS 2048
#define HDIM 512
#define DESCD 256

typedef unsigned short u16;
typedef __attribute__((ext_vector_type(8))) short bf16x8;   // 8 bf16 = 4 VGPRs
typedef __attribute__((ext_vector_type(8))) u16 u16x8;      // staging regs
typedef __attribute__((ext_vector_type(4))) float f32x4;    // MFMA acc

// async global->LDS: 16B per lane, dest = uniform base + lane*16
#define GLD_LDS(g, l)                                                          \
    __builtin_amdgcn_global_load_lds(                                          \
        (const __attribute__((address_space(1))) unsigned int*)(g),            \
        (__attribute__((address_space(3))) unsigned int*)(l), 16, 0, 0)

__device__ __forceinline__ float gelu_f(float x) {
    return 0.5f * x * (1.0f + erff(x * 0.70710678118654752f));
}
__device__ __forceinline__ float lrelu_f(float x) {
    return x > 0.0f ? x : 0.2f * x;
}
__device__ __forceinline__ float wave_reduce_sum(float v) {
#pragma unroll
    for (int off = 32; off > 0; off >>= 1) v += __shfl_down(v, off, 64);
    return v;
}

// ---- bf16 <-> f32 helpers (compute fp32, storage bf16) ----
__device__ __forceinline__ float bf2f(u16 u) { return __uint_as_float(((unsigned)u) << 16); }
__device__ __forceinline__ u16 f2bf(float f) {
    unsigned u = __float_as_uint(f);
    unsigned r = (u >> 16) & 1u;
    return (u16)((u + 0x7fffu + r) >> 16);
}
__device__ __forceinline__ void ld8b(const u16* p, float o[8]) {
    ushort4 v0 = *(const ushort4*)p;
    ushort4 v1 = *(const ushort4*)(p + 4);
    o[0] = bf2f(v0.x); o[1] = bf2f(v0.y); o[2] = bf2f(v0.z); o[3] = bf2f(v0.w);
    o[4] = bf2f(v1.x); o[5] = bf2f(v1.y); o[6] = bf2f(v1.z); o[7] = bf2f(v1.w);
}
__device__ __forceinline__ void st8b(u16* p, const float o[8]) {
    ushort4 a, b;
    a.x = f2bf(o[0]); a.y = f2bf(o[1]); a.z = f2bf(o[2]); a.w = f2bf(o[3]);
    b.x = f2bf(o[4]); b.y = f2bf(o[5]); b.z = f2bf(o[6]); b.w = f2bf(o[7]);
    *(ushort4*)p = a; *(ushort4*)(p + 4) = b;
}

// ---------------- utility ----------------
__global__ void k_zero(int* __restrict__ p, int n) {
    int i = blockIdx.x * blockDim.x + threadIdx.x;
    if (i < n) p[i] = 0;
}

// ---------------- single-launch weight convert (layout documented in launcher) -------
__global__ void k_cvtall(const float* __restrict__ gat_w,
                         const float* __restrict__ sage_wl,
                         const float* __restrict__ sage_wr,
                         const float* __restrict__ fc_w,
                         const float* __restrict__ a1_w,
                         u16* __restrict__ Wb) {
    int id = blockIdx.x * 256 + threadIdx.x;  // 1,835,008 total
    const float* src;
    int off;
    if (id < 524288) { src = gat_w; off = id; }
    else if (id < 786432) { src = sage_wl; off = id - 524288; }
    else if (id < 1048576) { src = sage_wr; off = id - 786432; }
    else if (id < 1703936) { src = fc_w; off = id - 1048576; }
    else { src = a1_w; off = id - 1703936; }
    Wb[id] = f2bf(src[off]);
}

// ---------------- CSR build (by dst) ----------------
__global__ void k_count(const int* __restrict__ dst, int* __restrict__ deg) {
    int e = blockIdx.x * blockDim.x + threadIdx.x;
    if (e < N_EDGES) atomicAdd(&deg[dst[e]], 1);
}

__global__ __launch_bounds__(1024) void k_scan(const int* __restrict__ deg,
                                               int* __restrict__ indptr,
                                               int* __restrict__ cursor) {
    __shared__ int part[1024];
    int t = threadIdx.x;
    int base = t * 64;
    int s = 0;
#pragma unroll
    for (int i = 0; i < 16; i++) {
        int4 v = *(const int4*)(deg + base + i * 4);
        s += v.x + v.y + v.z + v.w;
    }
    part[t] = s;
    __syncthreads();
    for (int off = 1; off < 1024; off <<= 1) {
        int v = (t >= off) ? part[t - off] : 0;
        __syncthreads();
        part[t] += v;
        __syncthreads();
    }
    int run = (t == 0) ? 0 : part[t - 1];
    for (int i = 0; i < 64; i++) {
        int d = deg[base + i];
        indptr[base + i] = run;
        cursor[base + i] = run;
        run += d;
    }
    if (t == 1023) indptr[N_NODES] = run;
}

__global__ void k_fill(const int* __restrict__ src, const int* __restrict__ dst,
                       int* __restrict__ cursor, int* __restrict__ col) {
    int e = blockIdx.x * blockDim.x + threadIdx.x;
    if (e < N_EDGES) {
        int d = dst[e];
        int pos = atomicAdd(&cursor[d], 1);
        col[pos] = src[e];
    }
}

// ---------------- vsrc/vdst (coalesced): v[h,k] = sum_c a[h,c] * W[h*512+c, k] -------
__global__ __launch_bounds__(256) void k_vproj(const float* __restrict__ gat_w,
                                               const float* __restrict__ asrc,
                                               const float* __restrict__ adst,
                                               float* __restrict__ vs,
                                               float* __restrict__ vd) {
    int h = blockIdx.x;
    int t = threadIdx.x;
    const float* W = gat_w + (size_t)h * HDIM * HDIM;
    float s0 = 0.f, s1 = 0.f, d0 = 0.f, d1 = 0.f;
    for (int c = 0; c < HDIM; c++) {
        float as = asrc[h * HDIM + c], ad = adst[h * HDIM + c];
        float w0 = W[(size_t)c * HDIM + t];
        float w1 = W[(size_t)c * HDIM + t + 256];
        s0 += as * w0; s1 += as * w1;
        d0 += ad * w0; d1 += ad * w1;
    }
    vs[h * HDIM + t] = s0; vs[h * HDIM + t + 256] = s1;
    vd[h * HDIM + t] = d0; vd[h * HDIM + t + 256] = d1;
}

// ---------------- GIN + fused attention coefficients ----------------
__global__ __launch_bounds__(256) void k_gin(const float* __restrict__ x,
                                             const int* __restrict__ indptr,
                                             const int* __restrict__ col,
                                             const float* __restrict__ gw,
                                             const float* __restrict__ gb,
                                             const float* __restrict__ vs,
                                             const float* __restrict__ vd,
                                             u16* __restrict__ h1,
                                             float* __restrict__ a_s,
                                             float* __restrict__ a_d) {
    __shared__ float w[HDIM * 9];
    __shared__ float b[HDIM];
    for (int idx = threadIdx.x; idx < HDIM * 9; idx += 256) w[idx] = gw[idx];
    for (int idx = threadIdx.x; idx < HDIM; idx += 256) b[idx] = gb[idx];
    __syncthreads();
    int wave = threadIdx.x >> 6, lane = threadIdx.x & 63;
    int i = blockIdx.x * 4 + wave;
    if (i >= N_NODES) return;
    float s[9];
#pragma unroll
    for (int k = 0; k < 9; k++) s[k] = x[i * 9 + k];
    int beg = indptr[i], end = indptr[i + 1];
    for (int e = beg; e < end; e++) {
        int j = col[e];
#pragma unroll
        for (int k = 0; k < 9; k++) s[k] += x[j * 9 + k];
    }
    float s0 = 0, d0 = 0, s1 = 0, d1 = 0;
#pragma unroll
    for (int q = 0; q < 8; q++) {
        int c = q * 64 + lane;
        float acc = b[c];
#pragma unroll
        for (int k = 0; k < 9; k++) acc += s[k] * w[c * 9 + k];
        float v = gelu_f(acc);
        h1[(size_t)i * HDIM + c] = f2bf(v);
        s0 += v * vs[c];
        d0 += v * vd[c];
        s1 += v * vs[HDIM + c];
        d1 += v * vd[HDIM + c];
    }
    s0 = wave_reduce_sum(s0);
    d0 = wave_reduce_sum(d0);
    s1 = wave_reduce_sum(s1);
    d1 = wave_reduce_sum(d1);
    if (lane == 0) {
        a_s[i * 2] = s0; a_s[i * 2 + 1] = s1;
        a_d[i * 2] = d0; a_d[i * 2 + 1] = d1;
    }
}

// ---------------- GAT softmax-aggregate: single pass, 2-edge unrolled (MLP=2) --------
__global__ __launch_bounds__(256) void k_gatagg(const u16* __restrict__ h1,
                                                const float* __restrict__ a_s,
                                                const float* __restrict__ a_d,
                                                const int* __restrict__ indptr,
                                                const int* __restrict__ col,
                                                u16* __restrict__ agg0,
                                                u16* __restrict__ agg1) {
    int wave = threadIdx.x >> 6, lane = threadIdx.x & 63;
    int i = blockIdx.x * 4 + wave;
    if (i >= N_NODES) return;
    int beg = indptr[i], end = indptr[i + 1];
    float ad0 = a_d[i * 2], ad1 = a_d[i * 2 + 1];
    float sl0 = expf(lrelu_f(a_s[i * 2] + ad0));
    float sl1 = expf(lrelu_f(a_s[i * 2 + 1] + ad1));
    float den0 = sl0, den1 = sl1;
    float acc0[8], acc1[8], hv[8];
    ld8b(h1 + (size_t)i * HDIM + lane * 8, hv);
#pragma unroll
    for (int r = 0; r < 8; r++) { acc0[r] = sl0 * hv[r]; acc1[r] = sl1 * hv[r]; }
    int e = beg;
    for (; e + 2 <= end; e += 2) {  // two independent row loads in flight
        int j0 = col[e], j1 = col[e + 1];
        float hva[8], hvb[8];
        ld8b(h1 + (size_t)j0 * HDIM + lane * 8, hva);
        ld8b(h1 + (size_t)j1 * HDIM + lane * 8, hvb);
        float w00 = expf(lrelu_f(a_s[j0 * 2] + ad0));
        float w01 = expf(lrelu_f(a_s[j0 * 2 + 1] + ad1));
        float w10 = expf(lrelu_f(a_s[j1 * 2] + ad0));
        float w11 = expf(lrelu_f(a_s[j1 * 2 + 1] + ad1));
        den0 += w00 + w10;
        den1 += w01 + w11;
#pragma unroll
        for (int r = 0; r < 8; r++) {
            acc0[r] += w00 * hva[r] + w10 * hvb[r];
            acc1[r] += w01 * hva[r] + w11 * hvb[r];
        }
    }
    if (e < end) {
        int j = col[e];
        float hva[8];
        ld8b(h1 + (size_t)j * HDIM + lane * 8, hva);
        float w0 = expf(lrelu_f(a_s[j * 2] + ad0));
        float w1 = expf(lrelu_f(a_s[j * 2 + 1] + ad1));
        den0 += w0;
        den1 += w1;
#pragma unroll
        for (int r = 0; r < 8; r++) {
            acc0[r] += w0 * hva[r];
            acc1[r] += w1 * hva[r];
        }
    }
    float inv0 = 0.5f / den0, inv1 = 0.5f / den1;  // head-mean folded
#pragma unroll
    for (int r = 0; r < 8; r++) { acc0[r] *= inv0; acc1[r] *= inv1; }
    st8b(agg0 + (size_t)i * HDIM + lane * 8, acc0);
    st8b(agg1 + (size_t)i * HDIM + lane * 8, acc1);
}

// ---------------- SAGE mean aggregation (2-edge unrolled) ----------------
__global__ __launch_bounds__(256) void k_sagemean(const u16* __restrict__ h2,
                                                  const int* __restrict__ indptr,
                                                  const int* __restrict__ col,
                                                  u16* __restrict__ mean) {
    int wave = threadIdx.x >> 6, lane = threadIdx.x & 63;
    int i = blockIdx.x * 4 + wave;
    if (i >= N_NODES) return;
    int beg = indptr[i], end = indptr[i + 1];
    float acc[8];
#pragma unroll
    for (int r = 0; r < 8; r++) acc[r] = 0.0f;
    int e = beg;
    for (; e + 2 <= end; e += 2) {
        int j0 = col[e], j1 = col[e + 1];
        float hva[8], hvb[8];
        ld8b(h2 + (size_t)j0 * HDIM + lane * 8, hva);
        ld8b(h2 + (size_t)j1 * HDIM + lane * 8, hvb);
#pragma unroll
        for (int r = 0; r < 8; r++) acc[r] += hva[r] + hvb[r];
    }
    if (e < end) {
        int j = col[e];
        float hva[8];
        ld8b(h2 + (size_t)j * HDIM + lane * 8, hva);
#pragma unroll
        for (int r = 0; r < 8; r++) acc[r] += hva[r];
    }
    float invc = 1.0f / fmaxf((float)(end - beg), 1.0f);
#pragma unroll
    for (int r = 0; r < 8; r++) acc[r] *= invc;
    st8b(mean + (size_t)i * HDIM + lane * 8, acc);
}

// ---------------- LDS-tiled MFMA GEMM (compile-time K) ----------------
// C = act(A0@W0^T [+ A1@W1^T] + bias). 128x128 tile, BK=64, 4 waves, 4x4 frags.
// bf16 panels via global_load_lds (linear LDS dest + pre-swizzled global src; read XOR
// matches). AF32: A fp32 reg-staged with convert; B via gload_lds. XCD block swizzle.
// POOL: fuse per-graph (32 contiguous rows) max/mean pooling into float comb[G,1280].
template <int KK, bool DUAL, bool POOL, bool AF32>
__global__ __launch_bounds__(256) void k_mgemm(const void* __restrict__ A0v,
                                               const u16* __restrict__ W0,
                                               const void* __restrict__ A1v,
                                               const u16* __restrict__ W1,
                                               const float* __restrict__ bias,
                                               u16* __restrict__ C, int ldc,
                                               float* __restrict__ comb) {
    __shared__ u16 sA[128 * 64];
    __shared__ u16 sB[128 * 64];
    int t = threadIdx.x;
    int wave = t >> 6, lane = t & 63;
    int wr = wave >> 1, wc = wave & 1;
    int l15 = lane & 15, l4 = lane >> 4;
    int bx, by;
    {
        int nwgx = gridDim.x;
        int nwg = nwgx * gridDim.y;
        int bid = blockIdx.y * nwgx + blockIdx.x;
        int q = nwg >> 3;
        int l = (bid & 7) * q + (bid >> 3);
        bx = l % nwgx;
        by = l / nwgx;
    }
    int row0 = by * 128;
    int c0 = bx * 128;

    // gload_lds source swizzle: 8 rows per 1KB instruction; lane l -> row +(l>>3),
    // global chunk (l&7)^(l>>3)  (rows are 8-aligned so row&7 == l>>3)
    int rowoff = lane >> 3;
    int gchunk = (lane & 7) ^ rowoff;

    f32x4 acc[4][4];
#pragma unroll
    for (int i = 0; i < 4; i++)
#pragma unroll
        for (int j = 0; j < 4; j++) acc[i][j] = (f32x4){0.f, 0.f, 0.f, 0.f};

    auto pass = [&](const void* Av, const u16* Wp) {
        const u16* ApU = (const u16*)Av;
        const float* ApF = (const float*)Av;
        for (int ks = 0; ks < KK / 64; ks++) {
            int k0 = ks * 64;
            u16x8 ga[4];
            if constexpr (AF32) {  // load+convert before barrier (overlap prev compute)
#pragma unroll
                for (int q = 0; q < 4; q++) {
                    int cid = q * 256 + t;
                    int row = cid >> 3, cb = cid & 7;
                    const float* p = ApF + (size_t)(row0 + row) * KK + k0 + cb * 8;
                    float4 f0 = *(const float4*)p;
                    float4 f1 = *(const float4*)(p + 4);
                    u16x8 v;
                    v[0] = f2bf(f0.x); v[1] = f2bf(f0.y); v[2] = f2bf(f0.z); v[3] = f2bf(f0.w);
                    v[4] = f2bf(f1.x); v[5] = f2bf(f1.y); v[6] = f2bf(f1.z); v[7] = f2bf(f1.w);
                    ga[q] = v;
                }
            }
            __syncthreads();  // previous K-step's LDS reads done
            if constexpr (AF32) {
#pragma unroll
                for (int q = 0; q < 4; q++) {
                    int cid = q * 256 + t;
                    int row = cid >> 3, cb = cid & 7;
                    *(u16x8*)(sA + row * 64 + ((cb ^ (row & 7)) * 8)) = ga[q];
                }
            } else {
#pragma unroll
                for (int q = 0; q < 4; q++) {
                    int r0 = wave * 32 + q * 8;
                    GLD_LDS(ApU + (size_t)(row0 + r0 + rowoff) * KK + k0 + gchunk * 8,
                            sA + r0 * 64);
                }
            }
#pragma unroll
            for (int q = 0; q < 4; q++) {
                int r0 = wave * 32 + q * 8;
                GLD_LDS(Wp + (size_t)(c0 + r0 + rowoff) * KK + k0 + gchunk * 8,
                        sB + r0 * 64);
            }
            __syncthreads();  // drain -> tiles ready
#pragma unroll
            for (int h = 0; h < 2; h++) {  // two K=32 halves of BK=64
                bf16x8 af[4], bfv[4];
                int cb = h * 4 + l4;
#pragma unroll
                for (int i = 0; i < 4; i++) {
                    int ra = wr * 64 + i * 16 + l15;
                    af[i] = *(const bf16x8*)(sA + ra * 64 + ((cb ^ (ra & 7)) * 8));
                    int rb = wc * 64 + i * 16 + l15;
                    bfv[i] = *(const bf16x8*)(sB + rb * 64 + ((cb ^ (rb & 7)) * 8));
                }
#pragma unroll
                for (int i = 0; i < 4; i++)
#pragma unroll
                    for (int j = 0; j < 4; j++)
                        acc[i][j] = __builtin_amdgcn_mfma_f32_16x16x32_bf16(af[i], bfv[j], acc[i][j], 0, 0, 0);
            }
        }
    };
    pass(A0v, W0);
    if constexpr (DUAL) pass(A1v, W1);

    if constexpr (!POOL) {
#pragma unroll
        for (int i = 0; i < 4; i++) {
            int rbase = row0 + wr * 64 + i * 16 + l4 * 4;
#pragma unroll
            for (int j = 0; j < 4; j++) {
                int colc = c0 + wc * 64 + j * 16 + l15;
                float bv = bias[colc];
#pragma unroll
                for (int r = 0; r < 4; r++)
                    C[(size_t)(rbase + r) * ldc + colc] = f2bf(gelu_f(acc[i][j][r] + bv));
            }
        }
    } else {
        // wave's 64 rows = exactly 2 graphs (32 contiguous nodes each)
#pragma unroll
        for (int gl = 0; gl < 2; gl++) {
            int g = (row0 >> 5) + wr * 2 + gl;
#pragma unroll
            for (int j = 0; j < 4; j++) {
                int colc = c0 + wc * 64 + j * 16 + l15;
                float bv = bias[colc];
                float mx = -1e30f, sm = 0.0f;
#pragma unroll
                for (int i = 0; i < 2; i++) {
#pragma unroll
                    for (int r = 0; r < 4; r++) {
                        float v = gelu_f(acc[gl * 2 + i][j][r] + bv);
                        mx = fmaxf(mx, v);
                        sm += v;
                    }
                }
                mx = fmaxf(mx, __shfl_xor(mx, 16, 64)); sm += __shfl_xor(sm, 16, 64);
                mx = fmaxf(mx, __shfl_xor(mx, 32, 64)); sm += __shfl_xor(sm, 32, 64);
                if (l4 == 0) {
                    comb[(size_t)g * 1280 + colc] = mx;
                    comb[(size_t)g * 1280 + 512 + colc] = sm * (1.0f / 32.0f);
                }
            }
        }
    }
}

// ---------------- descriptor copy into comb[:,1024:1280] ----------------
__global__ void k_desc(const float* __restrict__ desc, float* __restrict__ comb) {
    int idx = blockIdx.x * blockDim.x + threadIdx.x;
    int g = idx >> 8, c = idx & 255;
    comb[(size_t)g * 1280 + 1024 + c] = desc[(size_t)g * DESCD + c];
}

// ---------------- final row-dot: out = z1 @ a2_w.T + a2_b (z1 in bf16) ----------------
__global__ __launch_bounds__(256) void k_final(const u16* __restrict__ z1,
                                               const float* __restrict__ a2w,
                                               const float* __restrict__ a2b,
                                               float* __restrict__ out) {
    int wave = threadIdx.x >> 6, lane = threadIdx.x & 63;
    int g = blockIdx.x * 4 + wave;
    if (g >= N_GRAPHS) return;
    float s = 0.0f;
#pragma unroll
    for (int q = 0; q < 4; q++) {
        int c = q * 64 + lane;
        s += bf2f(z1[g * 256 + c]) * a2w[c];
    }
    s = wave_reduce_sum(s);
    if (lane == 0) out[g] = s + a2b[0];
}

// ---------------- launch ----------------
extern "C" void kernel_launch(void* const* d_in, const int* in_sizes, int n_in,
                              void* d_out, int out_size, void* d_ws, size_t ws_size,
                              hipStream_t stream) {
    (void)in_sizes; (void)n_in;
    const float* x = (const float*)d_in[0];
    const int* ei = (const int*)d_in[1];
    const int* src = ei;
    const int* dst = ei + N_EDGES;
    const float* desc = (const float*)d_in[3];
    const float* gin_w = (const float*)d_in[4];
    const float* gin_b = (const float*)d_in[5];
    const float* gat_w = (const float*)d_in[6];
    const float* gat_asrc = (const float*)d_in[7];
    const float* gat_adst = (const float*)d_in[8];
    const float* gat_bias = (const float*)d_in[9];
    const float* sage_wl = (const float*)d_in[10];
    const float* sage_bl = (const float*)d_in[11];
    const float* sage_wr = (const float*)d_in[12];
    const float* fc_w = (const float*)d_in[13];
    const float* fc_b = (const float*)d_in[14];
    const float* a1_w = (const float*)d_in[15];
    const float* a1_b = (const float*)d_in[16];
    const float* a2_w = (const float*)d_in[17];
    const float* a2_b = (const float*)d_in[18];
    float* out = (float*)d_out;

    if (ws_size < (size_t)200 * 1024 * 1024) {
        k_zero<<<(out_size + 255) / 256, 256, 0, stream>>>((int*)d_out, out_size);
        return;
    }

    char* wsp = (char*)d_ws;
    auto alloc = [&](size_t bytes) {
        char* p = wsp;
        wsp += (bytes + 255) & ~(size_t)255;
        return p;
    };
    int* deg = (int*)alloc((size_t)N_NODES * 4);
    int* indptr = (int*)alloc((size_t)(N_NODES + 1) * 4);
    int* cursor = (int*)alloc((size_t)N_NODES * 4);
    int* colv = (int*)alloc((size_t)N_EDGES * 4);
    float* a_s = (float*)alloc((size_t)N_NODES * 2 * 4);
    float* a_d = (float*)alloc((size_t)N_NODES * 2 * 4);
    float* vs = (float*)alloc((size_t)2 * HDIM * 4);
    float* vd = (float*)alloc((size_t)2 * HDIM * 4);
    // bf16 weights: gat(524288) | wl(262144) | wr(262144) | fc(655360) | a1(131072)
    u16* Wb = (u16*)alloc((size_t)1835008 * 2);
    size_t nodeb = (size_t)N_NODES * HDIM * 2;
    u16* R1 = (u16*)alloc(nodeb);  // h1 -> h2
    u16* R2 = (u16*)alloc(nodeb);  // agg0 -> mean
    u16* R3 = (u16*)alloc(nodeb);  // agg1 -> (comb/sf/z1 overlays)

    float* comb = (float*)R3;                              // [G,1280] fp32
    u16* sf = (u16*)(comb + (size_t)N_GRAPHS * 1280);      // [G,512] bf16
    u16* z1 = sf + (size_t)N_GRAPHS * 512;                 // [G,256] bf16

    u16* Wb0 = Wb;              // gat head0
    u16* Wb1 = Wb + 262144;     // gat head1
    u16* Wb2 = Wb + 524288;     // sage_wl
    u16* Wb3 = Wb + 786432;     // sage_wr
    u16* Wbfc = Wb + 1048576;   // fc_w
    u16* Wba1 = Wb + 1703936;   // a1_w

    // weight conversion (single launch, independent of graph work)
    k_cvtall<<<7168, 256, 0, stream>>>(gat_w, sage_wl, sage_wr, fc_w, a1_w, Wb);

    // CSR
    k_zero<<<N_NODES / 256, 256, 0, stream>>>(deg, N_NODES);
    k_count<<<N_EDGES / 256, 256, 0, stream>>>(dst, deg);
    k_scan<<<1, 1024, 0, stream>>>(deg, indptr, cursor);
    k_fill<<<N_EDGES / 256, 256, 0, stream>>>(src, dst, cursor, colv);

    // attention coefficient vectors (needed by fused GIN)
    k_vproj<<<2, 256, 0, stream>>>(gat_w, gat_asrc, gat_adst, vs, vd);

    // GIN -> h1 (R1) + fused attention coefficients
    k_gin<<<N_NODES / 4, 256, 0, stream>>>(x, indptr, colv, gin_w, gin_b, vs, vd,
                                           R1, a_s, a_d);

    // GAT aggregate h1 -> agg0 (R2), agg1 (R3)  [single pass, 2-unrolled]
    k_gatagg<<<N_NODES / 4, 256, 0, stream>>>(R1, a_s, a_d, indptr, colv, R2, R3);

    // h2 = gelu(agg0@W0^T + agg1@W1^T + b) -> R1   [MFMA, dual]
    k_mgemm<512, true, false, false><<<dim3(HDIM / 128, N_NODES / 128), 256, 0, stream>>>(
        R2, Wb0, R3, Wb1, gat_bias, R1, HDIM, nullptr);

    // SAGE mean of h2 -> R2  [2-unrolled]
    k_sagemean<<<N_NODES / 4, 256, 0, stream>>>(R1, indptr, colv, R2);

    // h3 = gelu(mean@wl^T + h2@wr^T + bl) fused with pooling -> comb  [MFMA, dual]
    k_mgemm<512, true, true, false><<<dim3(HDIM / 128, N_NODES / 128), 256, 0, stream>>>(
        R2, Wb2, R1, Wb3, sage_bl, nullptr, 0, comb);
    k_desc<<<N_GRAPHS, 256, 0, stream>>>(desc, comb);

    // sf = gelu(comb @ fc_w^T + fc_b)  [MFMA, fp32 A converted in staging]
    k_mgemm<1280, false, false, true><<<dim3(512 / 128, N_GRAPHS / 128), 256, 0, stream>>>(
        comb, Wbfc, nullptr, nullptr, fc_b, sf, 512, nullptr);

    // z1 = gelu(sf @ a1_w^T + a1_b)  [MFMA]
    k_mgemm<512, false, false, false><<<dim3(256 / 128, N_GRAPHS / 128), 256, 0, stream>>>(
        sf, Wba1, nullptr, nullptr, a1_b, z1, 256, nullptr);

    // out = z1 @ a2_w^T + a2_b
    k_final<<<N_GRAPHS / 4, 256, 0, stream>>>(z1, a2_w, a2_b, out);
}

// Round 16
// 595.490 us; speedup vs baseline: 1.0830x; 1.0830x over previous
//
#include <hip/hip_runtime.h>
#include <math.h>

#define N_NODES 65536
#define N_EDGES 262144
#define N_GRAPHS 2048
#define HDIM 512
#define DESCD 256

typedef unsigned short u16;
typedef __attribute__((ext_vector_type(8))) short bf16x8;   // 8 bf16 = 4 VGPRs
typedef __attribute__((ext_vector_type(8))) u16 u16x8;      // staging regs
typedef __attribute__((ext_vector_type(4))) float f32x4;    // MFMA acc

// async global->LDS: 16B per lane, dest = uniform base + lane*16
#define GLD_LDS(g, l)                                                          \
    __builtin_amdgcn_global_load_lds(                                          \
        (const __attribute__((address_space(1))) unsigned int*)(g),            \
        (__attribute__((address_space(3))) unsigned int*)(l), 16, 0, 0)

// fast gelu: tanh-form, max abs err ~3e-4 (below bf16 rounding of activations)
__device__ __forceinline__ float gelu_f(float x) {
    float u = x * (1.0f + 0.044715f * x * x);
    return x / (1.0f + __expf(-1.5957691216057308f * u));
}
__device__ __forceinline__ float lrelu_f(float x) {
    return x > 0.0f ? x : 0.2f * x;
}
__device__ __forceinline__ float wave_reduce_sum(float v) {
#pragma unroll
    for (int off = 32; off > 0; off >>= 1) v += __shfl_down(v, off, 64);
    return v;
}

// ---- bf16 <-> f32 helpers (compute fp32, storage bf16) ----
__device__ __forceinline__ float bf2f(u16 u) { return __uint_as_float(((unsigned)u) << 16); }
__device__ __forceinline__ u16 f2bf(float f) {
    unsigned u = __float_as_uint(f);
    unsigned r = (u >> 16) & 1u;
    return (u16)((u + 0x7fffu + r) >> 16);
}
__device__ __forceinline__ void ld8b(const u16* p, float o[8]) {
    ushort4 v0 = *(const ushort4*)p;
    ushort4 v1 = *(const ushort4*)(p + 4);
    o[0] = bf2f(v0.x); o[1] = bf2f(v0.y); o[2] = bf2f(v0.z); o[3] = bf2f(v0.w);
    o[4] = bf2f(v1.x); o[5] = bf2f(v1.y); o[6] = bf2f(v1.z); o[7] = bf2f(v1.w);
}
__device__ __forceinline__ void st8b(u16* p, const float o[8]) {
    ushort4 a, b;
    a.x = f2bf(o[0]); a.y = f2bf(o[1]); a.z = f2bf(o[2]); a.w = f2bf(o[3]);
    b.x = f2bf(o[4]); b.y = f2bf(o[5]); b.z = f2bf(o[6]); b.w = f2bf(o[7]);
    *(ushort4*)p = a; *(ushort4*)(p + 4) = b;
}

// ---------------- utility ----------------
__global__ void k_zero(int* __restrict__ p, int n) {
    int i = blockIdx.x * blockDim.x + threadIdx.x;
    if (i < n) p[i] = 0;
}

// ---------------- single-launch weight convert (layout documented in launcher) -------
__global__ void k_cvtall(const float* __restrict__ gat_w,
                         const float* __restrict__ sage_wl,
                         const float* __restrict__ sage_wr,
                         const float* __restrict__ fc_w,
                         const float* __restrict__ a1_w,
                         u16* __restrict__ Wb) {
    int id = blockIdx.x * 256 + threadIdx.x;  // 1,835,008 total
    const float* src;
    int off;
    if (id < 524288) { src = gat_w; off = id; }
    else if (id < 786432) { src = sage_wl; off = id - 524288; }
    else if (id < 1048576) { src = sage_wr; off = id - 786432; }
    else if (id < 1703936) { src = fc_w; off = id - 1048576; }
    else { src = a1_w; off = id - 1703936; }
    Wb[id] = f2bf(src[off]);
}

// ---------------- CSR build (by dst) ----------------
__global__ void k_count(const int* __restrict__ dst, int* __restrict__ deg) {
    int e = blockIdx.x * blockDim.x + threadIdx.x;
    if (e < N_EDGES) atomicAdd(&deg[dst[e]], 1);
}

__global__ __launch_bounds__(1024) void k_scan(const int* __restrict__ deg,
                                               int* __restrict__ indptr,
                                               int* __restrict__ cursor) {
    __shared__ int part[1024];
    int t = threadIdx.x;
    int base = t * 64;
    int s = 0;
#pragma unroll
    for (int i = 0; i < 16; i++) {
        int4 v = *(const int4*)(deg + base + i * 4);
        s += v.x + v.y + v.z + v.w;
    }
    part[t] = s;
    __syncthreads();
    for (int off = 1; off < 1024; off <<= 1) {
        int v = (t >= off) ? part[t - off] : 0;
        __syncthreads();
        part[t] += v;
        __syncthreads();
    }
    int run = (t == 0) ? 0 : part[t - 1];
    for (int i = 0; i < 64; i++) {
        int d = deg[base + i];
        indptr[base + i] = run;
        cursor[base + i] = run;
        run += d;
    }
    if (t == 1023) indptr[N_NODES] = run;
}

__global__ void k_fill(const int* __restrict__ src, const int* __restrict__ dst,
                       int* __restrict__ cursor, int* __restrict__ col) {
    int e = blockIdx.x * blockDim.x + threadIdx.x;
    if (e < N_EDGES) {
        int d = dst[e];
        int pos = atomicAdd(&cursor[d], 1);
        col[pos] = src[e];
    }
}

// ---------------- vsrc/vdst: 16 blocks (h x 8 row-chunks), atomicAdd reduce ----------
__global__ __launch_bounds__(256) void k_vproj(const float* __restrict__ gat_w,
                                               const float* __restrict__ asrc,
                                               const float* __restrict__ adst,
                                               float* __restrict__ vs,
                                               float* __restrict__ vd) {
    int h = blockIdx.x;
    int chunk = blockIdx.y;
    int t = threadIdx.x;
    const float* W = gat_w + (size_t)h * HDIM * HDIM;
    int cbeg = chunk * 64, cend = cbeg + 64;
    float s0 = 0.f, s1 = 0.f, d0 = 0.f, d1 = 0.f;
    for (int c = cbeg; c < cend; c++) {
        float as = asrc[h * HDIM + c], ad = adst[h * HDIM + c];
        float w0 = W[(size_t)c * HDIM + t];
        float w1 = W[(size_t)c * HDIM + t + 256];
        s0 += as * w0; s1 += as * w1;
        d0 += ad * w0; d1 += ad * w1;
    }
    atomicAdd(&vs[h * HDIM + t], s0);
    atomicAdd(&vs[h * HDIM + t + 256], s1);
    atomicAdd(&vd[h * HDIM + t], d0);
    atomicAdd(&vd[h * HDIM + t + 256], d1);
}

// ---------------- GIN + fused attention coefficients ----------------
__global__ __launch_bounds__(256) void k_gin(const float* __restrict__ x,
                                             const int* __restrict__ indptr,
                                             const int* __restrict__ col,
                                             const float* __restrict__ gw,
                                             const float* __restrict__ gb,
                                             const float* __restrict__ vs,
                                             const float* __restrict__ vd,
                                             u16* __restrict__ h1,
                                             float* __restrict__ a_s,
                                             float* __restrict__ a_d) {
    __shared__ float w[HDIM * 9];
    __shared__ float b[HDIM];
    for (int idx = threadIdx.x; idx < HDIM * 9; idx += 256) w[idx] = gw[idx];
    for (int idx = threadIdx.x; idx < HDIM; idx += 256) b[idx] = gb[idx];
    __syncthreads();
    int wave = threadIdx.x >> 6, lane = threadIdx.x & 63;
    int i = blockIdx.x * 4 + wave;
    if (i >= N_NODES) return;
    float s[9];
#pragma unroll
    for (int k = 0; k < 9; k++) s[k] = x[i * 9 + k];
    int beg = indptr[i], end = indptr[i + 1];
    for (int e = beg; e < end; e++) {
        int j = col[e];
#pragma unroll
        for (int k = 0; k < 9; k++) s[k] += x[j * 9 + k];
    }
    float s0 = 0, d0 = 0, s1 = 0, d1 = 0;
#pragma unroll
    for (int q = 0; q < 8; q++) {
        int c = q * 64 + lane;
        float acc = b[c];
#pragma unroll
        for (int k = 0; k < 9; k++) acc += s[k] * w[c * 9 + k];
        float v = gelu_f(acc);
        h1[(size_t)i * HDIM + c] = f2bf(v);
        s0 += v * vs[c];
        d0 += v * vd[c];
        s1 += v * vs[HDIM + c];
        d1 += v * vd[HDIM + c];
    }
    s0 = wave_reduce_sum(s0);
    d0 = wave_reduce_sum(d0);
    s1 = wave_reduce_sum(s1);
    d1 = wave_reduce_sum(d1);
    if (lane == 0) {
        a_s[i * 2] = s0; a_s[i * 2 + 1] = s1;
        a_d[i * 2] = d0; a_d[i * 2 + 1] = d1;
    }
}

// ---------------- GAT softmax-aggregate: single pass, 2-edge unrolled ----------------
__global__ __launch_bounds__(256) void k_gatagg(const u16* __restrict__ h1,
                                                const float* __restrict__ a_s,
                                                const float* __restrict__ a_d,
                                                const int* __restrict__ indptr,
                                                const int* __restrict__ col,
                                                u16* __restrict__ agg0,
                                                u16* __restrict__ agg1) {
    int wave = threadIdx.x >> 6, lane = threadIdx.x & 63;
    int i = blockIdx.x * 4 + wave;
    if (i >= N_NODES) return;
    int beg = indptr[i], end = indptr[i + 1];
    float ad0 = a_d[i * 2], ad1 = a_d[i * 2 + 1];
    float sl0 = __expf(lrelu_f(a_s[i * 2] + ad0));
    float sl1 = __expf(lrelu_f(a_s[i * 2 + 1] + ad1));
    float den0 = sl0, den1 = sl1;
    float acc0[8], acc1[8], hv[8];
    ld8b(h1 + (size_t)i * HDIM + lane * 8, hv);
#pragma unroll
    for (int r = 0; r < 8; r++) { acc0[r] = sl0 * hv[r]; acc1[r] = sl1 * hv[r]; }
    int e = beg;
    for (; e + 2 <= end; e += 2) {  // two independent row loads in flight
        int j0 = col[e], j1 = col[e + 1];
        float hva[8], hvb[8];
        ld8b(h1 + (size_t)j0 * HDIM + lane * 8, hva);
        ld8b(h1 + (size_t)j1 * HDIM + lane * 8, hvb);
        float w00 = __expf(lrelu_f(a_s[j0 * 2] + ad0));
        float w01 = __expf(lrelu_f(a_s[j0 * 2 + 1] + ad1));
        float w10 = __expf(lrelu_f(a_s[j1 * 2] + ad0));
        float w11 = __expf(lrelu_f(a_s[j1 * 2 + 1] + ad1));
        den0 += w00 + w10;
        den1 += w01 + w11;
#pragma unroll
        for (int r = 0; r < 8; r++) {
            acc0[r] += w00 * hva[r] + w10 * hvb[r];
            acc1[r] += w01 * hva[r] + w11 * hvb[r];
        }
    }
    if (e < end) {
        int j = col[e];
        float hva[8];
        ld8b(h1 + (size_t)j * HDIM + lane * 8, hva);
        float w0 = __expf(lrelu_f(a_s[j * 2] + ad0));
        float w1 = __expf(lrelu_f(a_s[j * 2 + 1] + ad1));
        den0 += w0;
        den1 += w1;
#pragma unroll
        for (int r = 0; r < 8; r++) {
            acc0[r] += w0 * hva[r];
            acc1[r] += w1 * hva[r];
        }
    }
    float inv0 = 0.5f / den0, inv1 = 0.5f / den1;  // head-mean folded
#pragma unroll
    for (int r = 0; r < 8; r++) { acc0[r] *= inv0; acc1[r] *= inv1; }
    st8b(agg0 + (size_t)i * HDIM + lane * 8, acc0);
    st8b(agg1 + (size_t)i * HDIM + lane * 8, acc1);
}

// ---------------- SAGE mean aggregation (2-edge unrolled) ----------------
__global__ __launch_bounds__(256) void k_sagemean(const u16* __restrict__ h2,
                                                  const int* __restrict__ indptr,
                                                  const int* __restrict__ col,
                                                  u16* __restrict__ mean) {
    int wave = threadIdx.x >> 6, lane = threadIdx.x & 63;
    int i = blockIdx.x * 4 + wave;
    if (i >= N_NODES) return;
    int beg = indptr[i], end = indptr[i + 1];
    float acc[8];
#pragma unroll
    for (int r = 0; r < 8; r++) acc[r] = 0.0f;
    int e = beg;
    for (; e + 2 <= end; e += 2) {
        int j0 = col[e], j1 = col[e + 1];
        float hva[8], hvb[8];
        ld8b(h2 + (size_t)j0 * HDIM + lane * 8, hva);
        ld8b(h2 + (size_t)j1 * HDIM + lane * 8, hvb);
#pragma unroll
        for (int r = 0; r < 8; r++) acc[r] += hva[r] + hvb[r];
    }
    if (e < end) {
        int j = col[e];
        float hva[8];
        ld8b(h2 + (size_t)j * HDIM + lane * 8, hva);
#pragma unroll
        for (int r = 0; r < 8; r++) acc[r] += hva[r];
    }
    float invc = 1.0f / fmaxf((float)(end - beg), 1.0f);
#pragma unroll
    for (int r = 0; r < 8; r++) acc[r] *= invc;
    st8b(mean + (size_t)i * HDIM + lane * 8, acc);
}

// ---------------- LDS-tiled MFMA GEMM (compile-time K) ----------------
// C = act(A0@W0^T [+ A1@W1^T] + bias). 128x128 tile, BK=64, 4 waves, 4x4 frags.
// bf16 panels via global_load_lds (linear LDS dest + pre-swizzled global src; read XOR
// matches). AF32: A fp32 reg-staged with convert; B via gload_lds. XCD block swizzle.
// POOL: fuse per-graph (32 contiguous rows) max/mean pooling into float comb[G,1280].
template <int KK, bool DUAL, bool POOL, bool AF32>
__global__ __launch_bounds__(256) void k_mgemm(const void* __restrict__ A0v,
                                               const u16* __restrict__ W0,
                                               const void* __restrict__ A1v,
                                               const u16* __restrict__ W1,
                                               const float* __restrict__ bias,
                                               u16* __restrict__ C, int ldc,
                                               float* __restrict__ comb) {
    __shared__ u16 sA[128 * 64];
    __shared__ u16 sB[128 * 64];
    int t = threadIdx.x;
    int wave = t >> 6, lane = t & 63;
    int wr = wave >> 1, wc = wave & 1;
    int l15 = lane & 15, l4 = lane >> 4;
    int bx, by;
    {
        int nwgx = gridDim.x;
        int nwg = nwgx * gridDim.y;
        int bid = blockIdx.y * nwgx + blockIdx.x;
        int q = nwg >> 3;
        int l = (bid & 7) * q + (bid >> 3);
        bx = l % nwgx;
        by = l / nwgx;
    }
    int row0 = by * 128;
    int c0 = bx * 128;

    // gload_lds source swizzle: 8 rows per 1KB instruction; lane l -> row +(l>>3),
    // global chunk (l&7)^(l>>3)  (rows are 8-aligned so row&7 == l>>3)
    int rowoff = lane >> 3;
    int gchunk = (lane & 7) ^ rowoff;

    f32x4 acc[4][4];
#pragma unroll
    for (int i = 0; i < 4; i++)
#pragma unroll
        for (int j = 0; j < 4; j++) acc[i][j] = (f32x4){0.f, 0.f, 0.f, 0.f};

    auto pass = [&](const void* Av, const u16* Wp) {
        const u16* ApU = (const u16*)Av;
        const float* ApF = (const float*)Av;
        for (int ks = 0; ks < KK / 64; ks++) {
            int k0 = ks * 64;
            u16x8 ga[4];
            if constexpr (AF32) {  // load+convert before barrier (overlap prev compute)
#pragma unroll
                for (int q = 0; q < 4; q++) {
                    int cid = q * 256 + t;
                    int row = cid >> 3, cb = cid & 7;
                    const float* p = ApF + (size_t)(row0 + row) * KK + k0 + cb * 8;
                    float4 f0 = *(const float4*)p;
                    float4 f1 = *(const float4*)(p + 4);
                    u16x8 v;
                    v[0] = f2bf(f0.x); v[1] = f2bf(f0.y); v[2] = f2bf(f0.z); v[3] = f2bf(f0.w);
                    v[4] = f2bf(f1.x); v[5] = f2bf(f1.y); v[6] = f2bf(f1.z); v[7] = f2bf(f1.w);
                    ga[q] = v;
                }
            }
            __syncthreads();  // previous K-step's LDS reads done
            if constexpr (AF32) {
#pragma unroll
                for (int q = 0; q < 4; q++) {
                    int cid = q * 256 + t;
                    int row = cid >> 3, cb = cid & 7;
                    *(u16x8*)(sA + row * 64 + ((cb ^ (row & 7)) * 8)) = ga[q];
                }
            } else {
#pragma unroll
                for (int q = 0; q < 4; q++) {
                    int r0 = wave * 32 + q * 8;
                    GLD_LDS(ApU + (size_t)(row0 + r0 + rowoff) * KK + k0 + gchunk * 8,
                            sA + r0 * 64);
                }
            }
#pragma unroll
            for (int q = 0; q < 4; q++) {
                int r0 = wave * 32 + q * 8;
                GLD_LDS(Wp + (size_t)(c0 + r0 + rowoff) * KK + k0 + gchunk * 8,
                        sB + r0 * 64);
            }
            __syncthreads();  // drain -> tiles ready
#pragma unroll
            for (int h = 0; h < 2; h++) {  // two K=32 halves of BK=64
                bf16x8 af[4], bfv[4];
                int cb = h * 4 + l4;
#pragma unroll
                for (int i = 0; i < 4; i++) {
                    int ra = wr * 64 + i * 16 + l15;
                    af[i] = *(const bf16x8*)(sA + ra * 64 + ((cb ^ (ra & 7)) * 8));
                    int rb = wc * 64 + i * 16 + l15;
                    bfv[i] = *(const bf16x8*)(sB + rb * 64 + ((cb ^ (rb & 7)) * 8));
                }
#pragma unroll
                for (int i = 0; i < 4; i++)
#pragma unroll
                    for (int j = 0; j < 4; j++)
                        acc[i][j] = __builtin_amdgcn_mfma_f32_16x16x32_bf16(af[i], bfv[j], acc[i][j], 0, 0, 0);
            }
        }
    };
    pass(A0v, W0);
    if constexpr (DUAL) pass(A1v, W1);

    if constexpr (!POOL) {
#pragma unroll
        for (int i = 0; i < 4; i++) {
            int rbase = row0 + wr * 64 + i * 16 + l4 * 4;
#pragma unroll
            for (int j = 0; j < 4; j++) {
                int colc = c0 + wc * 64 + j * 16 + l15;
                float bv = bias[colc];
#pragma unroll
                for (int r = 0; r < 4; r++)
                    C[(size_t)(rbase + r) * ldc + colc] = f2bf(gelu_f(acc[i][j][r] + bv));
            }
        }
    } else {
        // wave's 64 rows = exactly 2 graphs (32 contiguous nodes each)
#pragma unroll
        for (int gl = 0; gl < 2; gl++) {
            int g = (row0 >> 5) + wr * 2 + gl;
#pragma unroll
            for (int j = 0; j < 4; j++) {
                int colc = c0 + wc * 64 + j * 16 + l15;
                float bv = bias[colc];
                float mx = -1e30f, sm = 0.0f;
#pragma unroll
                for (int i = 0; i < 2; i++) {
#pragma unroll
                    for (int r = 0; r < 4; r++) {
                        float v = gelu_f(acc[gl * 2 + i][j][r] + bv);
                        mx = fmaxf(mx, v);
                        sm += v;
                    }
                }
                mx = fmaxf(mx, __shfl_xor(mx, 16, 64)); sm += __shfl_xor(sm, 16, 64);
                mx = fmaxf(mx, __shfl_xor(mx, 32, 64)); sm += __shfl_xor(sm, 32, 64);
                if (l4 == 0) {
                    comb[(size_t)g * 1280 + colc] = mx;
                    comb[(size_t)g * 1280 + 512 + colc] = sm * (1.0f / 32.0f);
                }
            }
        }
    }
}

// ---------------- descriptor copy into comb[:,1024:1280] ----------------
__global__ void k_desc(const float* __restrict__ desc, float* __restrict__ comb) {
    int idx = blockIdx.x * blockDim.x + threadIdx.x;
    int g = idx >> 8, c = idx & 255;
    comb[(size_t)g * 1280 + 1024 + c] = desc[(size_t)g * DESCD + c];
}

// ---------------- final row-dot: out = z1 @ a2_w.T + a2_b (z1 in bf16) ----------------
__global__ __launch_bounds__(256) void k_final(const u16* __restrict__ z1,
                                               const float* __restrict__ a2w,
                                               const float* __restrict__ a2b,
                                               float* __restrict__ out) {
    int wave = threadIdx.x >> 6, lane = threadIdx.x & 63;
    int g = blockIdx.x * 4 + wave;
    if (g >= N_GRAPHS) return;
    float s = 0.0f;
#pragma unroll
    for (int q = 0; q < 4; q++) {
        int c = q * 64 + lane;
        s += bf2f(z1[g * 256 + c]) * a2w[c];
    }
    s = wave_reduce_sum(s);
    if (lane == 0) out[g] = s + a2b[0];
}

// ---------------- launch ----------------
extern "C" void kernel_launch(void* const* d_in, const int* in_sizes, int n_in,
                              void* d_out, int out_size, void* d_ws, size_t ws_size,
                              hipStream_t stream) {
    (void)in_sizes; (void)n_in;
    const float* x = (const float*)d_in[0];
    const int* ei = (const int*)d_in[1];
    const int* src = ei;
    const int* dst = ei + N_EDGES;
    const float* desc = (const float*)d_in[3];
    const float* gin_w = (const float*)d_in[4];
    const float* gin_b = (const float*)d_in[5];
    const float* gat_w = (const float*)d_in[6];
    const float* gat_asrc = (const float*)d_in[7];
    const float* gat_adst = (const float*)d_in[8];
    const float* gat_bias = (const float*)d_in[9];
    const float* sage_wl = (const float*)d_in[10];
    const float* sage_bl = (const float*)d_in[11];
    const float* sage_wr = (const float*)d_in[12];
    const float* fc_w = (const float*)d_in[13];
    const float* fc_b = (const float*)d_in[14];
    const float* a1_w = (const float*)d_in[15];
    const float* a1_b = (const float*)d_in[16];
    const float* a2_w = (const float*)d_in[17];
    const float* a2_b = (const float*)d_in[18];
    float* out = (float*)d_out;

    if (ws_size < (size_t)200 * 1024 * 1024) {
        k_zero<<<(out_size + 255) / 256, 256, 0, stream>>>((int*)d_out, out_size);
        return;
    }

    char* wsp = (char*)d_ws;
    auto alloc = [&](size_t bytes) {
        char* p = wsp;
        wsp += (bytes + 255) & ~(size_t)255;
        return p;
    };
    int* deg = (int*)alloc((size_t)N_NODES * 4);
    int* indptr = (int*)alloc((size_t)(N_NODES + 1) * 4);
    int* cursor = (int*)alloc((size_t)N_NODES * 4);
    int* colv = (int*)alloc((size_t)N_EDGES * 4);
    float* a_s = (float*)alloc((size_t)N_NODES * 2 * 4);
    float* a_d = (float*)alloc((size_t)N_NODES * 2 * 4);
    float* vs = (float*)alloc((size_t)2 * HDIM * 4);
    float* vd = (float*)alloc((size_t)2 * HDIM * 4);
    // bf16 weights: gat(524288) | wl(262144) | wr(262144) | fc(655360) | a1(131072)
    u16* Wb = (u16*)alloc((size_t)1835008 * 2);
    size_t nodeb = (size_t)N_NODES * HDIM * 2;
    u16* R1 = (u16*)alloc(nodeb);  // h1 -> h2
    u16* R2 = (u16*)alloc(nodeb);  // agg0 -> mean
    u16* R3 = (u16*)alloc(nodeb);  // agg1 -> (comb/sf/z1 overlays)

    float* comb = (float*)R3;                              // [G,1280] fp32
    u16* sf = (u16*)(comb + (size_t)N_GRAPHS * 1280);      // [G,512] bf16
    u16* z1 = sf + (size_t)N_GRAPHS * 512;                 // [G,256] bf16

    u16* Wb0 = Wb;              // gat head0
    u16* Wb1 = Wb + 262144;     // gat head1
    u16* Wb2 = Wb + 524288;     // sage_wl
    u16* Wb3 = Wb + 786432;     // sage_wr
    u16* Wbfc = Wb + 1048576;   // fc_w
    u16* Wba1 = Wb + 1703936;   // a1_w

    // weight conversion (single launch, independent of graph work)
    k_cvtall<<<7168, 256, 0, stream>>>(gat_w, sage_wl, sage_wr, fc_w, a1_w, Wb);

    // CSR
    k_zero<<<N_NODES / 256, 256, 0, stream>>>(deg, N_NODES);
    k_count<<<N_EDGES / 256, 256, 0, stream>>>(dst, deg);
    k_scan<<<1, 1024, 0, stream>>>(deg, indptr, cursor);
    k_fill<<<N_EDGES / 256, 256, 0, stream>>>(src, dst, cursor, colv);

    // attention coefficient vectors (zero + 16-block atomic reduce)
    k_zero<<<4, 256, 0, stream>>>((int*)vs, 2 * HDIM);
    k_zero<<<4, 256, 0, stream>>>((int*)vd, 2 * HDIM);
    k_vproj<<<dim3(2, 8), 256, 0, stream>>>(gat_w, gat_asrc, gat_adst, vs, vd);

    // GIN -> h1 (R1) + fused attention coefficients
    k_gin<<<N_NODES / 4, 256, 0, stream>>>(x, indptr, colv, gin_w, gin_b, vs, vd,
                                           R1, a_s, a_d);

    // GAT aggregate h1 -> agg0 (R2), agg1 (R3)  [single pass, 2-unrolled]
    k_gatagg<<<N_NODES / 4, 256, 0, stream>>>(R1, a_s, a_d, indptr, colv, R2, R3);

    // h2 = gelu(agg0@W0^T + agg1@W1^T + b) -> R1   [MFMA, dual]
    k_mgemm<512, true, false, false><<<dim3(HDIM / 128, N_NODES / 128), 256, 0, stream>>>(
        R2, Wb0, R3, Wb1, gat_bias, R1, HDIM, nullptr);

    // SAGE mean of h2 -> R2  [2-unrolled]
    k_sagemean<<<N_NODES / 4, 256, 0, stream>>>(R1, indptr, colv, R2);

    // h3 = gelu(mean@wl^T + h2@wr^T + bl) fused with pooling -> comb  [MFMA, dual]
    k_mgemm<512, true, true, false><<<dim3(HDIM / 128, N_NODES / 128), 256, 0, stream>>>(
        R2, Wb2, R1, Wb3, sage_bl, nullptr, 0, comb);
    k_desc<<<N_GRAPHS, 256, 0, stream>>>(desc, comb);

    // sf = gelu(comb @ fc_w^T + fc_b)  [MFMA, fp32 A converted in staging]
    k_mgemm<1280, false, false, true><<<dim3(512 / 128, N_GRAPHS / 128), 256, 0, stream>>>(
        comb, Wbfc, nullptr, nullptr, fc_b, sf, 512, nullptr);

    // z1 = gelu(sf @ a1_w^T + a1_b)  [MFMA]
    k_mgemm<512, false, false, false><<<dim3(256 / 128, N_GRAPHS / 128), 256, 0, stream>>>(
        sf, Wba1, nullptr, nullptr, a1_b, z1, 256, nullptr);

    // out = z1 @ a2_w^T + a2_b
    k_final<<<N_GRAPHS / 4, 256, 0, stream>>>(z1, a2_w, a2_b, out);
}